// Round 9
// baseline (73.275 us; speedup 1.0000x reference)
//
#include <hip/hip_runtime.h>

// Gaussian splat renderer: B=2, 9 params x 32x32 gaussians -> [B,3,128,128].
//
// CALIBRATION ROUND (also a correct kernel): r6 structure exactly (fused,
// LDS table, 2 px/lane, 1 block/CU, builtin packed math), but the render
// loop runs TWICE with a memory clobber between passes so the compiler
// cannot fold pass 2. All four accumulators (w, r, g, b) double; the final
// image = (2*Sr)/(2*Sw) is invariant (1e-8 eps shift ~1e-8 relative).
// Therefore: dur_us(this) - dur_us(r6=66.15) = K_loop, the true marginal
// cost of the render loop -- the number 8 rounds of A/B could not pin down
// because the kernel never appears in the top-5 counter rows (all >=39us
// slots are harness poison fills).
//   K_loop ~5us  -> loop is at the VALU-model floor; harness-dominated;
//                   declare roofline next round.
//   K_loop >=10us -> ds_read->VALU stall-bound at 4 waves/SIMD; fix with
//                   software-pipelined record prefetch.

#define NB   2
#define NG   1024            // gaussians per batch (32*32)
#define HOUT 128
#define WOUT 128
#define PSTRIDE 20           // floats per gaussian-PAIR record (18 used + pad)
#define NCHUNK 16

typedef float v2f __attribute__((ext_vector_type(2)));

__device__ __forceinline__ float fast_exp(float x) {
    return __builtin_amdgcn_exp2f(x * 1.4426950408889634f);
}
__device__ __forceinline__ float fast_sigmoid(float x) {
    float e = __builtin_amdgcn_exp2f(-x * 1.4426950408889634f);
    return __builtin_amdgcn_rcpf(1.0f + e);
}
__device__ __forceinline__ float fast_tanh(float x) {
    float e = __builtin_amdgcn_exp2f(-x * 2.8853900817779268f);
    return fmaf(2.0f, __builtin_amdgcn_rcpf(1.0f + e), -1.0f);
}

__global__ __launch_bounds__(1024) void gauss_fused(const float* __restrict__ params,
                                                    float* __restrict__ out) {
    __shared__ __align__(16) float gtab[(NG / 2) * PSTRIDE];  // 40 KB
    __shared__ float4 sred[NCHUNK][128];                      // 32 KB partials

    const int tx  = threadIdx.x;             // pixel lane   [0,64)
    const int ty  = threadIdx.y;             // chunk        [0,16)
    const int tid = ty * 64 + tx;
    const int blk = blockIdx.x;
    const int b   = blk >> 7;                // 128 blocks (rows) per batch
    const int row = blk & 127;               // image row
    const int pixb = row << 7;               // first pixel of this row

    // ---------------- per-gaussian setup: thread tid -> gaussian tid -------
    {
        const int n = tid;
        const int gh = n >> 5;
        const int gw = n & 31;

        const float* P = params + b * 9 * NG + n;   // channel stride = 1024
        float p0 = P[0 * NG];
        float p1 = P[1 * NG];
        float p2 = P[2 * NG];
        float p3 = P[3 * NG];
        float p4 = P[4 * NG];
        float p5 = P[5 * NG];
        float p6 = P[6 * NG];
        float p7 = P[7 * NG];
        float p8 = P[8 * NG];

        // base_grid: linspace(-31/32, 31/32, 32) -> -0.96875 + i/16; off 2/32
        float mux = -0.96875f + (float)gw * 0.0625f + fast_tanh(p0) * 0.0625f;
        float muy = -0.96875f + (float)gh * 0.0625f + fast_tanh(p1) * 0.0625f;

        // cov = L L^T + 1e-5 I,  L = [[e^a,0],[b,e^c]]
        float ea  = fast_exp(p2);
        float ec  = fast_exp(p4);
        float c00 = ea * ea + 1e-5f;
        float c01 = p3 * ea;
        float c11 = p3 * p3 + ec * ec + 1e-5f;
        float det = c00 * c11 - c01 * c01;
        float id  = 1.0f / det;            // exact divide: det can be ~1e-10
        float Sa  =  c11 * id;
        float Sb  = -c01 * id;
        float Sc  =  c00 * id;

        // fold -0.5*log2(e) so the render loop computes exp2 directly
        const float s = -0.72134752044448169f;   // -0.5 * log2(e)
        float A  = s * Sa;
        float B2 = 2.0f * s * Sb;
        float C  = s * Sc;

        float cr = fast_sigmoid(p5);
        float cg = fast_sigmoid(p6);
        float cb = fast_sigmoid(p7);
        float op = fast_sigmoid(p8);

        // pair-blocked layout: record (n>>1), half (n&1); field stride 2
        float* o = gtab + (n >> 1) * PSTRIDE + (n & 1);
        o[0]  = mux;  o[2]  = muy;  o[4]  = A;       o[6]  = B2;
        o[8]  = C;    o[10] = op;   o[12] = op * cr; o[14] = op * cg;
        o[16] = op * cb;
    }
    __syncthreads();

    // ---------------- render: 2 pixels per lane, same row ------------------
    const float py  = -1.0f + (float)row * (2.0f / 127.0f);
    const float pxA = -1.0f + (float)tx * (2.0f / 127.0f);
    const float pxB = -1.0f + (float)(tx + 64) * (2.0f / 127.0f);
    const v2f py2  = {py, py};
    const v2f pxA2 = {pxA, pxA};
    const v2f pxB2 = {pxB, pxB};

    // wave-uniform chunk base; uniform-address LDS reads broadcast.
    const v2f* __restrict__ gp =
        (const v2f*)(gtab + ty * (NG / 2 / NCHUNK) * PSTRIDE);

    v2f wsA = {0,0}, arA = {0,0}, agA = {0,0}, abA = {0,0};
    v2f wsB = {0,0}, arB = {0,0}, agB = {0,0}, abB = {0,0};

    #pragma unroll 1
    for (int pass = 0; pass < 2; ++pass) {
        #pragma unroll 4
        for (int j = 0; j < NG / 2 / NCHUNK; ++j) {     // 32 pair-iterations
            const v2f* __restrict__ r = gp + j * (PSTRIDE / 2);
            v2f mux2 = r[0], muy2 = r[1];
            v2f A2   = r[2], B22  = r[3], C2 = r[4];
            v2f op2  = r[5], ocr2 = r[6], ocg2 = r[7], ocb2 = r[8];

            // shared across the two pixels (same row => same dy)
            v2f dy   = py2 - muy2;
            v2f bdy  = B22 * dy;
            v2f cdy2 = (C2 * dy) * dy;
            const v2f clampv = {-28.853900817779268f, -28.853900817779268f};

            // pixel A
            v2f dxA = pxA2 - mux2;
            v2f eA  = __builtin_elementwise_fma(
                          dxA, __builtin_elementwise_fma(A2, dxA, bdy), cdy2);
            eA = __builtin_elementwise_max(eA, clampv);
            v2f kA = {__builtin_amdgcn_exp2f(eA.x), __builtin_amdgcn_exp2f(eA.y)};
            wsA = __builtin_elementwise_fma(op2,  kA, wsA);
            arA = __builtin_elementwise_fma(ocr2, kA, arA);
            agA = __builtin_elementwise_fma(ocg2, kA, agA);
            abA = __builtin_elementwise_fma(ocb2, kA, abA);

            // pixel B
            v2f dxB = pxB2 - mux2;
            v2f eB  = __builtin_elementwise_fma(
                          dxB, __builtin_elementwise_fma(A2, dxB, bdy), cdy2);
            eB = __builtin_elementwise_max(eB, clampv);
            v2f kB = {__builtin_amdgcn_exp2f(eB.x), __builtin_amdgcn_exp2f(eB.y)};
            wsB = __builtin_elementwise_fma(op2,  kB, wsB);
            arB = __builtin_elementwise_fma(ocr2, kB, arB);
            agB = __builtin_elementwise_fma(ocg2, kB, agB);
            abB = __builtin_elementwise_fma(ocb2, kB, abB);
        }
        // Block GVN/CSE from folding pass 2 into pass 0: compiler must assume
        // LDS contents changed, so it re-issues the reads and the math.
        asm volatile("" ::: "memory");
    }

    sred[ty][tx]      = make_float4(wsA.x + wsA.y, arA.x + arA.y,
                                    agA.x + agA.y, abA.x + abA.y);
    sred[ty][tx + 64] = make_float4(wsB.x + wsB.y, arB.x + arB.y,
                                    agB.x + agB.y, abB.x + abB.y);
    __syncthreads();

    // ---------------- combine chunks, normalize, store (128 px/block) ------
    // Accumulators are exactly 2x (two passes); image = (2R)/(2W) invariant.
    if (tid < 128) {
        float4 a = sred[0][tid];
        #pragma unroll
        for (int c = 1; c < NCHUNK; ++c) {
            float4 t4 = sred[c][tid];
            a.x += t4.x; a.y += t4.y; a.z += t4.z; a.w += t4.w;
        }
        float inv = 1.0f / (a.x + 1e-8f);
        float* ob = out + b * 3 * (HOUT * WOUT) + pixb + tid;
        ob[0]               = a.y * inv;
        ob[HOUT * WOUT]     = a.z * inv;
        ob[2 * HOUT * WOUT] = a.w * inv;
    }
}

extern "C" void kernel_launch(void* const* d_in, const int* in_sizes, int n_in,
                              void* d_out, int out_size, void* d_ws, size_t ws_size,
                              hipStream_t stream) {
    const float* params = (const float*)d_in[0];
    float* out = (float*)d_out;
    (void)d_ws; (void)ws_size;   // workspace intentionally unused

    // 2 batches * 128 rows = 256 blocks (1 per CU), 1024 threads each
    hipLaunchKernelGGL(gauss_fused, dim3(NB * 128), dim3(64, NCHUNK), 0, stream,
                       params, out);
}

// Round 10
// 64.339 us; speedup vs baseline: 1.1389x; 1.1389x over previous
//
#include <hip/hip_runtime.h>

// Gaussian splat renderer: B=2, 9 params x 32x32 gaussians -> [B,3,128,128].
//
// r6 structure (fused, LDS table, 2 px/lane, 1 block/CU) with ROW-FOLDED
// records. Evidence ledger (r0-r9):
//  - fixed harness floor ~55us (poison fill 39.6 + resets); kernel ~11us
//  - r9 calibration (doubled loop): K_loop = 7.1us marginal; VALU-issue
//    bound (LDS-BW refuted r6, scalarization refuted r8)
//  - per-iter cost model: 18 pk (4cyc) + 4 max (2cyc) + 4 trans ~ 80 cyc
// This round shrinks per-iter work:
//  1. each block renders ONE row -> dy = py - muy is block-uniform, so
//     bdy = B2*dy and cdy2 = (C*dy)*dy are precomputed in the setup phase
//     (same expressions, same rounding). Record: 9 -> 8 v2f = 4x ds_read_b128.
//  2. clamp dropped: e2 <= 0 structurally; lower clip only changes far-term
//     contribution from e^-20 (2e-9) to true exp -> <=2e-6 relative on the
//     normalized image, far below the 0.002 tolerance.
// Per-iter: 14 pk + 4 trans ~ 56 cyc -> loop ~5us (was 7.1).

#define NB   2
#define NG   1024            // gaussians per batch (32*32)
#define HOUT 128
#define WOUT 128
#define PSTRIDE 16           // floats per gaussian-PAIR record (8 v2f, 64B)
#define NCHUNK 16

typedef float v2f __attribute__((ext_vector_type(2)));

__device__ __forceinline__ float fast_exp(float x) {
    return __builtin_amdgcn_exp2f(x * 1.4426950408889634f);
}
__device__ __forceinline__ float fast_sigmoid(float x) {
    float e = __builtin_amdgcn_exp2f(-x * 1.4426950408889634f);
    return __builtin_amdgcn_rcpf(1.0f + e);
}
__device__ __forceinline__ float fast_tanh(float x) {
    float e = __builtin_amdgcn_exp2f(-x * 2.8853900817779268f);
    return fmaf(2.0f, __builtin_amdgcn_rcpf(1.0f + e), -1.0f);
}

__global__ __launch_bounds__(1024) void gauss_fused(const float* __restrict__ params,
                                                    float* __restrict__ out) {
    __shared__ __align__(16) float gtab[(NG / 2) * PSTRIDE];  // 32 KB
    __shared__ float4 sred[NCHUNK][128];                      // 32 KB partials

    const int tx  = threadIdx.x;             // pixel lane   [0,64)
    const int ty  = threadIdx.y;             // chunk        [0,16)
    const int tid = ty * 64 + tx;
    const int blk = blockIdx.x;
    const int b   = blk >> 7;                // 128 blocks (rows) per batch
    const int row = blk & 127;               // image row
    const int pixb = row << 7;               // first pixel of this row
    const float py = -1.0f + (float)row * (2.0f / 127.0f);   // block-uniform

    // ---------------- per-gaussian setup: thread tid -> gaussian tid -------
    // Row-folded: dy = py - muy is block-uniform per gaussian, so the
    // dy-dependent terms are computed ONCE here instead of per loop-iter.
    {
        const int n = tid;
        const int gh = n >> 5;
        const int gw = n & 31;

        const float* P = params + b * 9 * NG + n;   // channel stride = 1024
        float p0 = P[0 * NG];
        float p1 = P[1 * NG];
        float p2 = P[2 * NG];
        float p3 = P[3 * NG];
        float p4 = P[4 * NG];
        float p5 = P[5 * NG];
        float p6 = P[6 * NG];
        float p7 = P[7 * NG];
        float p8 = P[8 * NG];

        // base_grid: linspace(-31/32, 31/32, 32) -> -0.96875 + i/16; off 2/32
        float mux = -0.96875f + (float)gw * 0.0625f + fast_tanh(p0) * 0.0625f;
        float muy = -0.96875f + (float)gh * 0.0625f + fast_tanh(p1) * 0.0625f;

        // cov = L L^T + 1e-5 I,  L = [[e^a,0],[b,e^c]]
        float ea  = fast_exp(p2);
        float ec  = fast_exp(p4);
        float c00 = ea * ea + 1e-5f;
        float c01 = p3 * ea;
        float c11 = p3 * p3 + ec * ec + 1e-5f;
        float det = c00 * c11 - c01 * c01;
        float id  = 1.0f / det;            // exact divide: det can be ~1e-10
        float Sa  =  c11 * id;
        float Sb  = -c01 * id;
        float Sc  =  c00 * id;

        // fold -0.5*log2(e) so the render loop computes exp2 directly
        const float s = -0.72134752044448169f;   // -0.5 * log2(e)
        float A  = s * Sa;
        float B2 = 2.0f * s * Sb;
        float C  = s * Sc;

        // row folding (same expressions the loop used: B2*dy, (C*dy)*dy)
        float dy   = py - muy;
        float bdy  = B2 * dy;
        float cdy2 = (C * dy) * dy;

        float cr = fast_sigmoid(p5);
        float cg = fast_sigmoid(p6);
        float cb = fast_sigmoid(p7);
        float op = fast_sigmoid(p8);

        // pair-blocked layout: record (n>>1), half (n&1); field stride 2
        float* o = gtab + (n >> 1) * PSTRIDE + (n & 1);
        o[0]  = mux;      o[2]  = A;        o[4]  = bdy;      o[6]  = cdy2;
        o[8]  = op;       o[10] = op * cr;  o[12] = op * cg;  o[14] = op * cb;
    }
    __syncthreads();

    // ---------------- render: 2 pixels per lane, same row ------------------
    const float pxA = -1.0f + (float)tx * (2.0f / 127.0f);
    const float pxB = -1.0f + (float)(tx + 64) * (2.0f / 127.0f);
    const v2f pxA2 = {pxA, pxA};
    const v2f pxB2 = {pxB, pxB};

    // wave-uniform chunk base; uniform-address LDS reads broadcast.
    const v2f* __restrict__ gp =
        (const v2f*)(gtab + ty * (NG / 2 / NCHUNK) * PSTRIDE);

    v2f wsA = {0,0}, arA = {0,0}, agA = {0,0}, abA = {0,0};
    v2f wsB = {0,0}, arB = {0,0}, agB = {0,0}, abB = {0,0};

    #pragma unroll 4
    for (int j = 0; j < NG / 2 / NCHUNK; ++j) {     // 32 pair-iterations
        const v2f* __restrict__ r = gp + j * (PSTRIDE / 2);
        v2f mux2  = r[0], A2   = r[1], bdy2 = r[2], cdy22 = r[3];
        v2f op2   = r[4], ocr2 = r[5], ocg2 = r[6], ocb2  = r[7];

        // pixel A: e = (A*dx + bdy)*dx + cdy2   (<= 0 structurally; no clamp:
        // exp2 underflows to 0, vs reference's e^-20 = 2e-9 -> negligible)
        v2f dxA = pxA2 - mux2;
        v2f eA  = __builtin_elementwise_fma(
                      __builtin_elementwise_fma(A2, dxA, bdy2), dxA, cdy22);
        v2f kA = {__builtin_amdgcn_exp2f(eA.x), __builtin_amdgcn_exp2f(eA.y)};
        wsA = __builtin_elementwise_fma(op2,  kA, wsA);
        arA = __builtin_elementwise_fma(ocr2, kA, arA);
        agA = __builtin_elementwise_fma(ocg2, kA, agA);
        abA = __builtin_elementwise_fma(ocb2, kA, abA);

        // pixel B
        v2f dxB = pxB2 - mux2;
        v2f eB  = __builtin_elementwise_fma(
                      __builtin_elementwise_fma(A2, dxB, bdy2), dxB, cdy22);
        v2f kB = {__builtin_amdgcn_exp2f(eB.x), __builtin_amdgcn_exp2f(eB.y)};
        wsB = __builtin_elementwise_fma(op2,  kB, wsB);
        arB = __builtin_elementwise_fma(ocr2, kB, arB);
        agB = __builtin_elementwise_fma(ocg2, kB, agB);
        abB = __builtin_elementwise_fma(ocb2, kB, abB);
    }

    sred[ty][tx]      = make_float4(wsA.x + wsA.y, arA.x + arA.y,
                                    agA.x + agA.y, abA.x + abA.y);
    sred[ty][tx + 64] = make_float4(wsB.x + wsB.y, arB.x + arB.y,
                                    agB.x + agB.y, abB.x + abB.y);
    __syncthreads();

    // ---------------- combine chunks, normalize, store (128 px/block) ------
    if (tid < 128) {
        float4 a = sred[0][tid];
        #pragma unroll
        for (int c = 1; c < NCHUNK; ++c) {
            float4 t4 = sred[c][tid];
            a.x += t4.x; a.y += t4.y; a.z += t4.z; a.w += t4.w;
        }
        float inv = 1.0f / (a.x + 1e-8f);
        float* ob = out + b * 3 * (HOUT * WOUT) + pixb + tid;
        ob[0]               = a.y * inv;
        ob[HOUT * WOUT]     = a.z * inv;
        ob[2 * HOUT * WOUT] = a.w * inv;
    }
}

extern "C" void kernel_launch(void* const* d_in, const int* in_sizes, int n_in,
                              void* d_out, int out_size, void* d_ws, size_t ws_size,
                              hipStream_t stream) {
    const float* params = (const float*)d_in[0];
    float* out = (float*)d_out;
    (void)d_ws; (void)ws_size;   // workspace intentionally unused

    // 2 batches * 128 rows = 256 blocks (1 per CU), 1024 threads each
    hipLaunchKernelGGL(gauss_fused, dim3(NB * 128), dim3(64, NCHUNK), 0, stream,
                       params, out);
}